// Round 1
// baseline (562.284 us; speedup 1.0000x reference)
//
#include <hip/hip_runtime.h>
#include <cfloat>

#define BB   32
#define VV   2048
#define KNB  40
#define FIN  64
#define DD   4
#define PP   64
#define NFO  128               // FILT
#define NN   (BB*VV)           // 65536

static __device__ __forceinline__ float fast_tanh(float z) {
    z = fminf(fmaxf(z, -15.f), 15.f);
    float e = __expf(2.f * z);
    return (e - 1.f) / (e + 1.f);
}

// ---------------------------------------------------------------------------
// Kernel 1: coords = x@W_s + b_s (N x 4), feats = x@W_f + b_f (N x 64)
// One wave per row (wave-uniform x row -> broadcast loads), lane = out col.
// ---------------------------------------------------------------------------
__global__ __launch_bounds__(256) void k_embed(
    const float* __restrict__ x, const float* __restrict__ Ws,
    const float* __restrict__ bs, const float* __restrict__ Wf,
    const float* __restrict__ bf, float* __restrict__ coords,
    float* __restrict__ feats)
{
    const int row = blockIdx.x * 4 + (threadIdx.x >> 6);
    const int p   = threadIdx.x & 63;
    const float* xr = x + (size_t)row * FIN;

    float acc = bf[p];
    #pragma unroll 16
    for (int k = 0; k < FIN; ++k)
        acc += xr[k] * Wf[k * PP + p];
    feats[(size_t)row * PP + p] = acc;

    if (p < DD) {
        float ca = bs[p];
        #pragma unroll 16
        for (int k = 0; k < FIN; ++k)
            ca += xr[k] * Ws[k * DD + p];
        coords[(size_t)row * DD + p] = ca;
    }
}

// ---------------------------------------------------------------------------
// Kernel 2: exact top-40 KNN (excluding self) + weighted max/mean pooling.
// Block = 256 thr = 4 waves; wave == one row per phase; 16 rows per block.
// Per row: 32 d2 in VGPRs -> coarse 256-bin hist [0,64) -> fine 256-bin hist
// (width 0.25/256) -> ballot-compact candidates -> 64-lane bitonic sort by
// (d2, idx) -> lanes 0..39 are the exact top-40 (lax.top_k tie-break).
// ---------------------------------------------------------------------------
#define RPB 16
__global__ __launch_bounds__(256) void k_knn(
    const float* __restrict__ coords, const float* __restrict__ feats,
    float* __restrict__ collected)
{
    __shared__ float4 cpos[VV];      // 32 KB
    __shared__ float  csq[VV];       //  8 KB
    __shared__ int    hist[4][256];  //  4 KB  (per-wave)
    __shared__ float  candD[4][64];  //  1 KB
    __shared__ int    candI[4][64];  //  1 KB

    const int tid   = threadIdx.x;
    const int lane  = tid & 63;
    const int w     = tid >> 6;
    const int batch = blockIdx.x >> 7;      // VV/RPB = 128 chunks per batch
    const int chunk = blockIdx.x & 127;
    const int vbase = chunk * RPB;
    const float* cb = coords + (size_t)batch * VV * DD;

    for (int i = tid; i < VV; i += 256) {
        float4 c = *(const float4*)(cb + (size_t)i * 4);
        cpos[i] = c;
        csq[i]  = c.x*c.x + c.y*c.y + c.z*c.z + c.w*c.w;
    }
    __syncthreads();

    for (int rr = 0; rr < RPB / 4; ++rr) {
        const int v = vbase + rr * 4 + w;
        const float4 cv = cpos[v];
        const float  sv = csq[v];

        // ---- zero coarse hist ----
        #pragma unroll
        for (int j = 0; j < 4; ++j) hist[w][j * 64 + lane] = 0;
        __syncthreads();

        // ---- pass 1: d2 into regs + coarse histogram ----
        float d2loc[32];
        #pragma unroll
        for (int j = 0; j < 32; ++j) {
            const int i = lane + j * 64;
            float4 cw = cpos[i];
            float dot = cv.x*cw.x + cv.y*cw.y + cv.z*cw.z + cv.w*cw.w;
            float d2  = sv + csq[i] - 2.f * dot;
            if (i == v) d2 = FLT_MAX;
            d2loc[j] = d2;
            if (i != v) {
                int b1 = (int)fminf(fmaxf(d2 * 4.f, 0.f), 255.f);
                atomicAdd(&hist[w][b1], 1);
            }
        }
        __syncthreads();

        // ---- scan coarse hist: g1 = bin of 40th value, nb1 = count below ----
        int g1, nb1;
        {
            int h0 = hist[w][lane*4+0], h1 = hist[w][lane*4+1];
            int h2 = hist[w][lane*4+2], h3 = hist[w][lane*4+3];
            int local = h0 + h1 + h2 + h3;
            int incl  = local;
            #pragma unroll
            for (int off = 1; off < 64; off <<= 1) {
                int t = __shfl_up(incl, off);
                if (lane >= off) incl += t;
            }
            int excl = incl - local;
            bool pred = (excl < KNB) && (excl + local >= KNB);
            unsigned long long m = __ballot(pred);
            int src = __ffsll(m) - 1;
            int gg = 255, nnb = 0;
            if (pred) {
                int c = excl, hh[4] = {h0, h1, h2, h3}, found = -1;
                #pragma unroll
                for (int j = 0; j < 4; ++j) {
                    if (found < 0 && c + hh[j] >= KNB) { found = j; nnb = c; }
                    c += hh[j];
                }
                gg = lane * 4 + found;
            }
            g1  = __shfl(gg, src);
            nb1 = __shfl(nnb, src);
        }
        __syncthreads();

        // ---- zero + fine histogram inside coarse bin g1 ----
        #pragma unroll
        for (int j = 0; j < 4; ++j) hist[w][j * 64 + lane] = 0;
        __syncthreads();
        const float lo = (float)g1 * 0.25f;
        #pragma unroll
        for (int j = 0; j < 32; ++j) {
            const int i = lane + j * 64;
            if (i != v) {
                float d2 = d2loc[j];
                int b1 = (int)fminf(fmaxf(d2 * 4.f, 0.f), 255.f);
                if (b1 == g1) {
                    int b2 = (int)fminf(fmaxf((d2 - lo) * 1024.f, 0.f), 255.f);
                    atomicAdd(&hist[w][b2], 1);
                }
            }
        }
        __syncthreads();

        // ---- scan fine hist with need2 = 40 - nb1 ----
        int g2;
        {
            const int need2 = KNB - nb1;
            int h0 = hist[w][lane*4+0], h1 = hist[w][lane*4+1];
            int h2 = hist[w][lane*4+2], h3 = hist[w][lane*4+3];
            int local = h0 + h1 + h2 + h3;
            int incl  = local;
            #pragma unroll
            for (int off = 1; off < 64; off <<= 1) {
                int t = __shfl_up(incl, off);
                if (lane >= off) incl += t;
            }
            int excl = incl - local;
            bool pred = (excl < need2) && (excl + local >= need2);
            unsigned long long m = __ballot(pred);
            int src = __ffsll(m) - 1;
            int gg = 255;
            if (pred) {
                int c = excl, hh[4] = {h0, h1, h2, h3}, found = -1;
                #pragma unroll
                for (int j = 0; j < 4; ++j) {
                    if (found < 0 && c + hh[j] >= need2) found = j;
                    c += hh[j];
                }
                gg = lane * 4 + found;
            }
            g2 = __shfl(gg, src);
        }
        __syncthreads();

        // ---- compact candidates (bin1<g1, or bin1==g1 && bin2<=g2) ----
        int total = 0;
        #pragma unroll
        for (int j = 0; j < 32; ++j) {
            const int i = lane + j * 64;
            float d2 = d2loc[j];
            bool flag = false;
            if (i != v) {
                int b1 = (int)fminf(fmaxf(d2 * 4.f, 0.f), 255.f);
                if (b1 < g1) flag = true;
                else if (b1 == g1) {
                    int b2 = (int)fminf(fmaxf((d2 - lo) * 1024.f, 0.f), 255.f);
                    flag = (b2 <= g2);
                }
            }
            unsigned long long m = __ballot(flag);
            if (flag) {
                int pos = total + (int)__popcll(m & ((1ull << lane) - 1ull));
                if (pos < 64) { candD[w][pos] = d2; candI[w][pos] = i; }
            }
            total += (int)__popcll(m);
        }
        if (total > 64) total = 64;   // overflow impossible in practice
        __syncthreads();

        // ---- 64-lane bitonic sort ascending by (d2, idx) ----
        float sd; int si;
        if (lane < total) { sd = candD[w][lane]; si = candI[w][lane]; }
        else              { sd = FLT_MAX;        si = 0x7fffffff;     }
        #pragma unroll
        for (int kk = 2; kk <= 64; kk <<= 1) {
            #pragma unroll
            for (int jj = kk >> 1; jj > 0; jj >>= 1) {
                float od = __shfl_xor(sd, jj);
                int   oi = __shfl_xor(si, jj);
                bool asc      = ((lane & kk) == 0);
                bool keepMin  = (asc == ((lane & jj) == 0));
                bool otherLess = (od < sd) || (od == sd && oi < si);
                if (otherLess == keepMin) { sd = od; si = oi; }
            }
        }

        // ---- pooling: lanes 0..39 hold the 40 nearest ----
        float wgt = 0.f;
        if (lane < KNB) {
            float4 cn = cpos[si];
            float dx = cv.x - cn.x, dy = cv.y - cn.y;
            float dz = cv.z - cn.z, dw = cv.w - cn.w;
            float dist = dx*dx + dy*dy + dz*dz + dw*dw;   // reference's direct form
            wgt = __expf(-10.f * dist);
        }
        float mx = -FLT_MAX, sm = 0.f;
        const float* fb = feats + (size_t)batch * VV * PP;
        #pragma unroll 8
        for (int j = 0; j < KNB; ++j) {
            float wj = __shfl(wgt, j);
            int   ij = __shfl(si, j);
            float f  = fb[(size_t)ij * PP + lane];
            float nv = f * wj;
            mx = fmaxf(mx, nv);
            sm += nv;
        }
        float* outp = collected + (size_t)(batch * VV + v) * (2 * PP);
        outp[lane]      = mx;
        outp[PP + lane] = sm * (1.f / KNB);
        __syncthreads();
    }
}

// ---------------------------------------------------------------------------
// Kernel 3: out = tanh(concat(x, collected) @ W_out + b_out), (N x 192)@(192 x 128)
// Block: 64 rows x 128 cols, 4x8 register micro-tile per thread, k-chunks of 16.
// Reads collected == d_out and overwrites the same rows afterwards (block-local,
// ordered by the k-loop -> safe).
// ---------------------------------------------------------------------------
__global__ __launch_bounds__(256) void k_out(
    const float* __restrict__ x, const float* __restrict__ collected,
    const float* __restrict__ Wout, const float* __restrict__ bout,
    float* __restrict__ out)
{
    __shared__ float As[64][20];    // +4 pad: a-reads 2-way (free) banks
    __shared__ float Bs[16][128];
    const int tid = threadIdx.x;
    const int tx  = tid & 15;       // col group: cols tx*4..+3 and 64+tx*4..+3
    const int ty  = tid >> 4;       // row group: rows ty*4..+3
    const int row0 = blockIdx.x * 64;

    float acc[4][8];
    #pragma unroll
    for (int i = 0; i < 4; ++i)
        #pragma unroll
        for (int j = 0; j < 8; ++j) acc[i][j] = 0.f;

    for (int k0 = 0; k0 < 192; k0 += 16) {
        {   // stage A tile (64 x 16), float4 per thread
            const int e = tid * 4;
            const int r = e >> 4, kk = e & 15;
            const float* src = (k0 < 64)
                ? (x + (size_t)(row0 + r) * FIN + (k0 + kk))
                : (collected + (size_t)(row0 + r) * 128 + (k0 - 64 + kk));
            *(float4*)&As[r][kk] = *(const float4*)src;
        }
        #pragma unroll
        for (int rep = 0; rep < 2; ++rep) {   // stage B tile (16 x 128)
            const int e = (tid + rep * 256) * 4;
            const int kk = e >> 7, c = e & 127;
            *(float4*)&Bs[kk][c] = *(const float4*)(Wout + (size_t)(k0 + kk) * 128 + c);
        }
        __syncthreads();
        #pragma unroll
        for (int kk = 0; kk < 16; ++kk) {
            float a[4];
            #pragma unroll
            for (int i = 0; i < 4; ++i) a[i] = As[ty * 4 + i][kk];
            float4 b0 = *(const float4*)&Bs[kk][tx * 4];
            float4 b1 = *(const float4*)&Bs[kk][64 + tx * 4];
            #pragma unroll
            for (int i = 0; i < 4; ++i) {
                acc[i][0] += a[i] * b0.x; acc[i][1] += a[i] * b0.y;
                acc[i][2] += a[i] * b0.z; acc[i][3] += a[i] * b0.w;
                acc[i][4] += a[i] * b1.x; acc[i][5] += a[i] * b1.y;
                acc[i][6] += a[i] * b1.z; acc[i][7] += a[i] * b1.w;
            }
        }
        __syncthreads();
    }

    #pragma unroll
    for (int i = 0; i < 4; ++i) {
        const int row = row0 + ty * 4 + i;
        float4 o0, o1;
        o0.x = fast_tanh(acc[i][0] + bout[tx*4+0]);
        o0.y = fast_tanh(acc[i][1] + bout[tx*4+1]);
        o0.z = fast_tanh(acc[i][2] + bout[tx*4+2]);
        o0.w = fast_tanh(acc[i][3] + bout[tx*4+3]);
        o1.x = fast_tanh(acc[i][4] + bout[64+tx*4+0]);
        o1.y = fast_tanh(acc[i][5] + bout[64+tx*4+1]);
        o1.z = fast_tanh(acc[i][6] + bout[64+tx*4+2]);
        o1.w = fast_tanh(acc[i][7] + bout[64+tx*4+3]);
        *(float4*)(out + (size_t)row * 128 + tx * 4)      = o0;
        *(float4*)(out + (size_t)row * 128 + 64 + tx * 4) = o1;
    }
}

// ---------------------------------------------------------------------------
extern "C" void kernel_launch(void* const* d_in, const int* in_sizes, int n_in,
                              void* d_out, int out_size, void* d_ws, size_t ws_size,
                              hipStream_t stream)
{
    const float* x    = (const float*)d_in[0];
    // d_in[1] = row_splits: uniform arange(B+1)*V — structure is fixed, unused.
    const float* Ws   = (const float*)d_in[2];
    const float* bs   = (const float*)d_in[3];
    const float* Wf   = (const float*)d_in[4];
    const float* bf   = (const float*)d_in[5];
    const float* Wout = (const float*)d_in[6];
    const float* bout = (const float*)d_in[7];
    float* out = (float*)d_out;

    float* coords = (float*)d_ws;                                        // 1 MB
    float* feats  = (float*)((char*)d_ws + (size_t)NN * DD * sizeof(float)); // 16 MB
    float* collected = out;  // reuse d_out as scratch for pooled features

    hipLaunchKernelGGL(k_embed, dim3(NN / 4), dim3(256), 0, stream,
                       x, Ws, bs, Wf, bf, coords, feats);
    hipLaunchKernelGGL(k_knn, dim3(BB * (VV / RPB)), dim3(256), 0, stream,
                       coords, feats, collected);
    hipLaunchKernelGGL(k_out, dim3(NN / 64), dim3(256), 0, stream,
                       x, collected, Wout, bout, out);
}